// Round 2
// baseline (560.705 us; speedup 1.0000x reference)
//
#include <hip/hip_runtime.h>
#include <math.h>

#define Bsz 8
#define Dd  128
#define Tt  4096
#define Kk  1024
#define NQ  8
#define BT  (Bsz*Tt)        // 32768 points
#define MT  128             // points per block (4 row-groups x 32)
#define NTHR 512
#define WV  8
#define DELTA 0.05f         // >= 10x rigorous |approx-exact| score bound

typedef float f32x4 __attribute__((ext_vector_type(4)));
typedef short short8 __attribute__((ext_vector_type(8)));

__device__ __forceinline__ unsigned short f2bf(float x) {   // RNE f32->bf16
    unsigned u = __float_as_uint(x);
    u += 0x7FFF + ((u >> 16) & 1);
    return (unsigned short)(u >> 16);
}
__device__ __forceinline__ float bf2f(unsigned short h) {
    return __uint_as_float(((unsigned)h) << 16);
}

// async global->LDS, 16B per lane. LDS dest must be wave-uniform; HW adds
// lane*16. Global src is per-lane.
__device__ __forceinline__ void gload_lds16(const void* g, void* l) {
    __builtin_amdgcn_global_load_lds(
        (const __attribute__((address_space(1))) unsigned int*)g,
        (__attribute__((address_space(3))) unsigned int*)l, 16, 0, 0);
}

// ---------------------------------------------------------------------------
// init: transpose x (B,D,T) -> resid (B,T,D)
// ---------------------------------------------------------------------------
__global__ void k_init(const float* __restrict__ x,
                       float* __restrict__ resid) {
    __shared__ float tile[32][33];
    int b  = blockIdx.z;
    int t0 = blockIdx.x * 32, d0 = blockIdx.y * 32;
    int tx = threadIdx.x, ty = threadIdx.y;   // 32 x 8
    #pragma unroll
    for (int k = 0; k < 4; k++) {
        int d = d0 + ty + k * 8;
        tile[ty + k * 8][tx] = x[((size_t)(b * Dd + d)) * Tt + t0 + tx];
    }
    __syncthreads();
    #pragma unroll
    for (int k = 0; k < 4; k++) {
        int t = t0 + ty + k * 8;
        resid[((size_t)(b * Tt + t)) * Dd + d0 + tx] = tile[tx][ty + k * 8];
    }
}

// ---------------------------------------------------------------------------
// k_prep: split codebook into hi/lo bf16, pre-swizzled into MFMA B-fragment
// order. B-frag (16x16x32 bf16): lane holds col n=lane&15, k=quad*8+j.
// Layout per (q, tile): 8192 B = [ch kc0..3 (1KB each) | cl kc0..3].
// ---------------------------------------------------------------------------
__global__ void k_prep(const float* __restrict__ cb, char* __restrict__ bswz) {
    int ln = threadIdx.x;                 // 64
    int kc = blockIdx.x & 3;
    int t  = (blockIdx.x >> 2) & 63;
    int q  = blockIdx.x >> 8;
    int code = t * 16 + (ln & 15);
    int d0   = kc * 32 + (ln >> 4) * 8;
    const float* src = cb + ((size_t)(q * Kk + code)) * Dd + d0;
    float v[8];
    *(float4*)&v[0] = *(const float4*)src;
    *(float4*)&v[4] = *(const float4*)(src + 4);
    short8 h, l;
    #pragma unroll
    for (int j = 0; j < 8; j++) {
        unsigned short hu = f2bf(v[j]);
        h[j] = (short)hu;
        l[j] = (short)f2bf(v[j] - bf2f(hu));   // exact remainder, then RNE
    }
    char* base = bswz + ((size_t)(q * 64 + t)) * 8192;
    *(short8*)(base + kc * 1024 + ln * 16) = h;
    *(short8*)(base + 4096 + kc * 1024 + ln * 16) = l;
}

// ---------------------------------------------------------------------------
// c2[q][k] = sum_d cb[q][k][d]^2 (exact f32) ; zero commit accumulators
// ---------------------------------------------------------------------------
__global__ void k_c2(const float* __restrict__ cb,
                     float* __restrict__ c2,
                     double* __restrict__ commits) {
    int row  = blockIdx.x * 4 + (threadIdx.x >> 6);
    int lane = threadIdx.x & 63;
    const float* p = cb + (size_t)row * Dd;
    float a = p[lane], b = p[lane + 64];
    float s = a * a + b * b;
    #pragma unroll
    for (int off = 32; off; off >>= 1) s += __shfl_down(s, off);
    if (lane == 0) c2[row] = s;
    if (blockIdx.x == 0 && threadIdx.x < NQ) commits[threadIdx.x] = 0.0;
}

// exact f32 chain, d ascending, rlds XOR-swizzled row — numeric order
// identical to the validated version (same fma sequence).
__device__ __forceinline__ float exact_score_sw(const float* __restrict__ rldsb,
                                                int p,
                                                const float* __restrict__ crow,
                                                float c2v) {
    const f32x4* r4 = (const f32x4*)rldsb;
    const f32x4* c4 = (const f32x4*)crow;
    int rb = p * 32, sw = p & 7;
    float a = 0.0f;
    #pragma unroll
    for (int d4 = 0; d4 < 32; d4++) {
        f32x4 r = r4[rb + (d4 ^ sw)];
        f32x4 c = c4[d4];
        a = fmaf(r[0], c[0], a); a = fmaf(r[1], c[1], a);
        a = fmaf(r[2], c[2], a); a = fmaf(r[3], c[3], a);
    }
    return fmaf(-2.0f, a, c2v);
}

// ---------------------------------------------------------------------------
// Fused persistent RVQ. 256 blocks x 512 thr (8 waves). Each wave owns 32
// points (2 A-frag sets) and half the codebook (waves 0-3: codes 0-511,
// waves 4-7: 512-1023) -> B-frag LDS reads per point*code halved vs r1.
// B tile pairs double-buffered in LDS via global_load_lds (counted vmcnt,
// raw s_barrier, 1 barrier/tile, no register round-trip). rlds XOR-swizzled
// (conflict-free A-prep/STE). Certification numerics bit-identical: per-half
// sorted triples merged with the same comparator (disjoint ordered ranges).
// ---------------------------------------------------------------------------
__global__ __launch_bounds__(NTHR, 2) void k_rvq_fused(
        float* __restrict__ resid,         // in: initial (B,T,D); out: final
        const float* __restrict__ cb,      // (NQ,K,D) f32
        const char*  __restrict__ bswz,    // (NQ*64 tiles) * 8192 B
        const float* __restrict__ c2g,     // (NQ,K) exact f32
        float* __restrict__ codes_f,       // (NQ,BT)
        double* __restrict__ commits) {    // (NQ)
    __shared__ float rlds[MT * Dd];        // 64 KB, XOR-swizzled f32x4 rows
    __shared__ float c2s[Kk];              // 4 KB
    __shared__ f32x4 bbuf[2][2][512];      // 32 KB [par][half][slice]
    __shared__ float fA1[MT], fA2[MT], fA3[MT];
    __shared__ float fB1[MT], fB2[MT], fB3[MT];
    __shared__ int   iA1[MT], iA2[MT], iB1[MT], iB2[MT];
    __shared__ int   sidxs[MT];
    __shared__ int   nfall, flist[MT];
    __shared__ float fwv[WV]; __shared__ int fwi[WV];
    __shared__ float csum[WV];

    const int tid  = threadIdx.x;
    const int w    = tid >> 6, ln = tid & 63;
    const int quad = ln >> 4,  m  = ln & 15;
    const int wg   = w & 3,    half = w >> 2;
    const int toff = half * 32;            // tile offset within stage
    const int base = blockIdx.x * MT;
    const int prow0 = wg * 32 + m;         // set-a row for this lane
    const int prow1 = wg * 32 + 16 + m;    // set-b row

    f32x4* r4 = (f32x4*)rlds;

    // block residual -> swizzled LDS (coalesced, once)
    {
        const f32x4* src = (const f32x4*)(resid + (size_t)base * Dd);
        #pragma unroll
        for (int i = 0; i < (MT * Dd / 4) / NTHR; i++) {    // 8 iters
            int idx = tid + i * NTHR;
            int row = idx >> 5, c4 = idx & 31;
            r4[row * 32 + (c4 ^ (row & 7))] = src[idx];
        }
    }
    __syncthreads();

    #pragma unroll 1
    for (int q = 0; q < NQ; q++) {
        const float* cbq = cb + (size_t)q * Kk * Dd;
        const char*  bsq = bswz + (size_t)q * 64 * 8192;
        #pragma unroll
        for (int i = 0; i < Kk / NTHR; i++)                 // 2 iters
            c2s[tid + i * NTHR] = c2g[q * Kk + tid + i * NTHR];
        if (tid == 0) nfall = 0;

        // A-fragments (2 sets of 16 rows) from swizzled rlds
        short8 Ah0[4], Al0[4], Ah1[4], Al1[4];
        #pragma unroll
        for (int kc = 0; kc < 4; kc++) {
            int c4a = kc * 8 + quad * 2;
            float v[8];
            short8 h, l;
            *(f32x4*)&v[0] = r4[prow0 * 32 + (c4a ^ (prow0 & 7))];
            *(f32x4*)&v[4] = r4[prow0 * 32 + ((c4a + 1) ^ (prow0 & 7))];
            #pragma unroll
            for (int j = 0; j < 8; j++) {
                unsigned short hu = f2bf(v[j]);
                h[j] = (short)hu;
                l[j] = (short)f2bf(v[j] - bf2f(hu));
            }
            Ah0[kc] = h; Al0[kc] = l;
            *(f32x4*)&v[0] = r4[prow1 * 32 + (c4a ^ (prow1 & 7))];
            *(f32x4*)&v[4] = r4[prow1 * 32 + ((c4a + 1) ^ (prow1 & 7))];
            #pragma unroll
            for (int j = 0; j < 8; j++) {
                unsigned short hu = f2bf(v[j]);
                h[j] = (short)hu;
                l[j] = (short)f2bf(v[j] - bf2f(hu));
            }
            Ah1[kc] = h; Al1[kc] = l;
        }

        // per-lane top-3 state, 2 sets x 4 point-slots
        float b1a[4], b2a[4], b3a[4], b1b[4], b2b[4], b3b[4];
        int   i1a[4], i2a[4], i1b[4], i2b[4];
        #pragma unroll
        for (int j = 0; j < 4; j++) {
            b1a[j] = INFINITY; b2a[j] = INFINITY; b3a[j] = INFINITY;
            b1b[j] = INFINITY; b2b[j] = INFINITY; b3b[j] = INFINITY;
            i1a[j] = 0; i2a[j] = 0; i1b[j] = 0; i2b[j] = 0;
        }
        __syncthreads();   // c2s ready; prev-stage bbuf fully consumed

        // prologue: stage pair 0 (wave w stages slice w of both tiles)
        gload_lds16(bsq + (size_t)toff * 0 + 0 * 8192 + w * 1024 + ln * 16,
                    (char*)&bbuf[0][0][0] + w * 1024);
        gload_lds16(bsq + (size_t)32 * 8192 + w * 1024 + ln * 16,
                    (char*)&bbuf[0][1][0] + w * 1024);
        int par = 0;

        #pragma unroll 1
        for (int s = 0; s < 32; s++) {
            asm volatile("s_waitcnt vmcnt(0)" ::: "memory");
            __builtin_amdgcn_s_barrier();          // all slices of pair s in;
            __builtin_amdgcn_sched_barrier(0);     // reads of pair s-1 retired
            if (s + 1 < 32) {                      // prefetch pair s+1
                gload_lds16(bsq + (size_t)(s + 1) * 8192 + w * 1024 + ln * 16,
                            (char*)&bbuf[par ^ 1][0][0] + w * 1024);
                gload_lds16(bsq + (size_t)(32 + s + 1) * 8192 + w * 1024 + ln * 16,
                            (char*)&bbuf[par ^ 1][1][0] + w * 1024);
            }
            const char* bb = (const char*)&bbuf[par][half][0];
            f32x4 a01a = {0.f,0.f,0.f,0.f}, a23a = {0.f,0.f,0.f,0.f};
            f32x4 a01b = {0.f,0.f,0.f,0.f}, a23b = {0.f,0.f,0.f,0.f};
            __builtin_amdgcn_s_setprio(1);
            #pragma unroll
            for (int kc = 0; kc < 4; kc++) {
                short8 ch = *(const short8*)(bb + kc * 1024 + ln * 16);
                short8 cl = *(const short8*)(bb + 4096 + kc * 1024 + ln * 16);
                if (kc < 2) {
                    a01a = __builtin_amdgcn_mfma_f32_16x16x32_bf16(Al0[kc], ch, a01a, 0, 0, 0);
                    a01a = __builtin_amdgcn_mfma_f32_16x16x32_bf16(Ah0[kc], cl, a01a, 0, 0, 0);
                    a01a = __builtin_amdgcn_mfma_f32_16x16x32_bf16(Ah0[kc], ch, a01a, 0, 0, 0);
                    a01b = __builtin_amdgcn_mfma_f32_16x16x32_bf16(Al1[kc], ch, a01b, 0, 0, 0);
                    a01b = __builtin_amdgcn_mfma_f32_16x16x32_bf16(Ah1[kc], cl, a01b, 0, 0, 0);
                    a01b = __builtin_amdgcn_mfma_f32_16x16x32_bf16(Ah1[kc], ch, a01b, 0, 0, 0);
                } else {
                    a23a = __builtin_amdgcn_mfma_f32_16x16x32_bf16(Al0[kc], ch, a23a, 0, 0, 0);
                    a23a = __builtin_amdgcn_mfma_f32_16x16x32_bf16(Ah0[kc], cl, a23a, 0, 0, 0);
                    a23a = __builtin_amdgcn_mfma_f32_16x16x32_bf16(Ah0[kc], ch, a23a, 0, 0, 0);
                    a23b = __builtin_amdgcn_mfma_f32_16x16x32_bf16(Al1[kc], ch, a23b, 0, 0, 0);
                    a23b = __builtin_amdgcn_mfma_f32_16x16x32_bf16(Ah1[kc], cl, a23b, 0, 0, 0);
                    a23b = __builtin_amdgcn_mfma_f32_16x16x32_bf16(Ah1[kc], ch, a23b, 0, 0, 0);
                }
            }
            __builtin_amdgcn_s_setprio(0);
            float c2v  = c2s[(toff + s) * 16 + m];
            int   code = (toff + s) * 16 + m;      // ascending per lane
            #pragma unroll
            for (int j = 0; j < 4; j++) {
                float sc = fmaf(-2.0f, a01a[j] + a23a[j], c2v);
                bool lt1 = sc < b1a[j];
                bool lt2 = sc < b2a[j];
                b3a[j] = __builtin_amdgcn_fmed3f(sc, b2a[j], b3a[j]);
                b2a[j] = __builtin_amdgcn_fmed3f(sc, b1a[j], b2a[j]);
                i2a[j] = lt1 ? i1a[j] : (lt2 ? code : i2a[j]);
                i1a[j] = lt1 ? code : i1a[j];
                b1a[j] = fminf(b1a[j], sc);
                float sd = fmaf(-2.0f, a01b[j] + a23b[j], c2v);
                bool mt1 = sd < b1b[j];
                bool mt2 = sd < b2b[j];
                b3b[j] = __builtin_amdgcn_fmed3f(sd, b2b[j], b3b[j]);
                b2b[j] = __builtin_amdgcn_fmed3f(sd, b1b[j], b2b[j]);
                i2b[j] = mt1 ? i1b[j] : (mt2 ? code : i2b[j]);
                i1b[j] = mt1 ? code : i1b[j];
                b1b[j] = fminf(b1b[j], sd);
            }
            asm volatile("s_waitcnt lgkmcnt(0)" ::: "memory");
            __builtin_amdgcn_sched_barrier(0);
            par ^= 1;
        }

        // per-set cross-lane merge of sorted triples over 16 cols, then
        // write per-half results to LDS (half 0 -> fA*, half 1 -> fB*)
        #pragma unroll
        for (int set = 0; set < 2; set++) {
            #pragma unroll
            for (int j = 0; j < 4; j++) {
                float v1 = set ? b1b[j] : b1a[j];
                float v2 = set ? b2b[j] : b2a[j];
                float v3 = set ? b3b[j] : b3a[j];
                int   a1 = set ? i1b[j] : i1a[j];
                int   a2 = set ? i2b[j] : i2a[j];
                #pragma unroll
                for (int off = 1; off < 16; off <<= 1) {
                    float w1 = __shfl_xor(v1, off); int j1 = __shfl_xor(a1, off);
                    float w2 = __shfl_xor(v2, off); int j2 = __shfl_xor(a2, off);
                    float w3 = __shfl_xor(v3, off);
                    bool aw = (v1 < w1) || (v1 == w1 && a1 < j1);
                    float x1 = aw ? v1 : w1, x2 = aw ? v2 : w2, x3 = aw ? v3 : w3;
                    int   y1 = aw ? a1 : j1, y2 = aw ? a2 : j2;
                    float z1 = aw ? w1 : v1, z2 = aw ? w2 : v2;
                    int   u1 = aw ? j1 : a1;
                    bool s2a = (x2 < z1) || (x2 == z1 && y2 < u1);
                    v1 = x1; a1 = y1;
                    v2 = s2a ? x2 : z1; a2 = s2a ? y2 : u1;
                    v3 = s2a ? fminf(x3, z1) : fminf(x2, z2);
                }
                if (m == 0) {
                    int p = wg * 32 + set * 16 + quad * 4 + j;
                    if (half == 0) {
                        fA1[p] = v1; fA2[p] = v2; fA3[p] = v3;
                        iA1[p] = a1; iA2[p] = a2;
                    } else {
                        fB1[p] = v1; fB2[p] = v2; fB3[p] = v3;
                        iB1[p] = a1; iB2[p] = a2;
                    }
                }
            }
        }
        __syncthreads();

        // decision: merge the two half-triples (same comparator; A-codes all
        // < B-codes so tie-breaks identical to a single ascending stream),
        // then DELTA certification + exact rescore of <=2 candidates.
        if (tid < MT) {
            int p = tid;
            float vA1 = fA1[p], vA2 = fA2[p], vA3 = fA3[p];
            int   aA1 = iA1[p], aA2 = iA2[p];
            float vB1 = fB1[p], vB2 = fB2[p], vB3 = fB3[p];
            int   aB1 = iB1[p], aB2 = iB2[p];
            bool aw = (vA1 < vB1) || (vA1 == vB1 && aA1 < aB1);
            float x1 = aw ? vA1 : vB1, x2 = aw ? vA2 : vB2, x3 = aw ? vA3 : vB3;
            int   y1 = aw ? aA1 : aB1, y2 = aw ? aA2 : aB2;
            float z1 = aw ? vB1 : vA1, z2 = aw ? vB2 : vA2;
            int   u1 = aw ? aB1 : aA1;
            bool s2a = (x2 < z1) || (x2 == z1 && y2 < u1);
            float v1 = x1;
            float v2 = s2a ? x2 : z1;
            float v3 = s2a ? fminf(x3, z1) : fminf(x2, z2);
            int   a1 = y1;
            int   a2 = s2a ? y2 : u1;
            if (v3 <= v1 + DELTA) {
                int sl = atomicAdd(&nfall, 1);     // rare: >=3 in window
                flist[sl] = p;
            } else {
                int bk = a1;
                if (v2 <= v1 + DELTA) {            // two candidates: rescore
                    float s1 = exact_score_sw(rlds, p, cbq + (size_t)a1 * Dd, c2s[a1]);
                    float s2 = exact_score_sw(rlds, p, cbq + (size_t)a2 * Dd, c2s[a2]);
                    if (s2 < s1 || (s2 == s1 && a2 < a1)) bk = a2;
                }
                sidxs[p] = bk;
                codes_f[(size_t)q * BT + base + p] = (float)bk;
            }
        }
        __syncthreads();

        // fallback: block-cooperative exact scan (executes ~never; exact)
        for (int fi = 0; fi < nfall; fi++) {
            int p = flist[fi];
            float bv = INFINITY; int bk = 0;
            #pragma unroll
            for (int c = 0; c < 2; c++) {
                int k = tid * 2 + c;               // ascending within thread
                float sc = exact_score_sw(rlds, p, cbq + (size_t)k * Dd, c2s[k]);
                if (sc < bv || (sc == bv && k < bk)) { bv = sc; bk = k; }
            }
            #pragma unroll
            for (int off = 32; off; off >>= 1) {
                float v2 = __shfl_xor(bv, off);
                int   k2 = __shfl_xor(bk, off);
                if (v2 < bv || (v2 == bv && k2 < bk)) { bv = v2; bk = k2; }
            }
            if (ln == 0) { fwv[w] = bv; fwi[w] = bk; }
            __syncthreads();
            if (tid == 0) {
                float v = fwv[0]; int k = fwi[0];
                #pragma unroll
                for (int w2 = 1; w2 < WV; w2++) {
                    if (fwv[w2] < v || (fwv[w2] == v && fwi[w2] < k)) {
                        v = fwv[w2]; k = fwi[w2];
                    }
                }
                sidxs[p] = k;
                codes_f[(size_t)q * BT + base + p] = (float)k;
            }
            __syncthreads();
        }
        __syncthreads();

        // fused STE update (swizzled rlds): thread -> point tid>>2,
        // dims [(tid&3)*32, +32). Per-element op order bit-identical.
        {
            int p = tid >> 2;
            int rb = p * 32, sw = p & 7, cb4 = (tid & 3) * 8;
            const float* qrow = cbq + ((size_t)sidxs[p]) * Dd + (tid & 3) * 32;
            float cacc = 0.0f;
            #pragma unroll
            for (int hh = 0; hh < 8; hh++) {
                f32x4 r  = r4[rb + ((cb4 + hh) ^ sw)];
                f32x4 qv = *(const f32x4*)(qrow + hh * 4);
                float t1x = qv[0] - r[0], t1y = qv[1] - r[1];
                float t1z = qv[2] - r[2], t1w = qv[3] - r[3];  // q - residual
                float qsx = r[0] + t1x, qsy = r[1] + t1y;
                float qsz = r[2] + t1z, qsw = r[3] + t1w;      // straight-through
                f32x4 nr = { r[0] - qsx, r[1] - qsy, r[2] - qsz, r[3] - qsw };
                r4[rb + ((cb4 + hh) ^ sw)] = nr;
                cacc = fmaf(t1x, t1x, cacc); cacc = fmaf(t1y, t1y, cacc);
                cacc = fmaf(t1z, t1z, cacc); cacc = fmaf(t1w, t1w, cacc);
            }
            #pragma unroll
            for (int off = 32; off; off >>= 1) cacc += __shfl_down(cacc, off);
            if (ln == 0) csum[w] = cacc;
        }
        __syncthreads();
        if (tid == 0) {
            double sd = 0.0;
            #pragma unroll
            for (int w2 = 0; w2 < WV; w2++) sd += (double)csum[w2];
            atomicAdd(commits + q, sd);
        }
        __syncthreads();   // gates next stage's c2s overwrite + A-prep
    }

    // final residual back to global (coalesced, once)
    {
        f32x4* dst = (f32x4*)(resid + (size_t)base * Dd);
        #pragma unroll
        for (int i = 0; i < (MT * Dd / 4) / NTHR; i++) {
            int idx = tid + i * NTHR;
            int row = idx >> 5, c4 = idx & 31;
            dst[idx] = r4[row * 32 + (c4 ^ (row & 7))];
        }
    }
}

// ---------------------------------------------------------------------------
// final: out(B,D,T) = x - resid_final^T
// ---------------------------------------------------------------------------
__global__ void k_final(const float* __restrict__ x,
                        const float* __restrict__ resid,
                        float* __restrict__ outq) {
    __shared__ float tile[32][33];
    int b  = blockIdx.z;
    int t0 = blockIdx.x * 32, d0 = blockIdx.y * 32;
    int tx = threadIdx.x, ty = threadIdx.y;   // 32 x 8
    #pragma unroll
    for (int k = 0; k < 4; k++) {
        int t = t0 + ty + k * 8;
        tile[ty + k * 8][tx] = resid[((size_t)(b * Tt + t)) * Dd + d0 + tx];
    }
    __syncthreads();
    #pragma unroll
    for (int k = 0; k < 4; k++) {
        int d = d0 + ty + k * 8;
        size_t o = ((size_t)(b * Dd + d)) * Tt + t0 + tx;
        outq[o] = x[o] - tile[tx][ty + k * 8];
    }
}

// ---------------------------------------------------------------------------
// scalars: bw = n_q * log2(K) * frame_rate ; penalty = mean(commits)
// ---------------------------------------------------------------------------
__global__ void k_scalars(const double* __restrict__ commits,
                          const int* __restrict__ frame_rate,
                          float* __restrict__ outs) {
    if (threadIdx.x == 0 && blockIdx.x == 0) {
        double s = 0.0;
        #pragma unroll
        for (int q = 0; q < NQ; q++) s += commits[q];
        double per_elem = s / ((double)NQ * (double)BT * (double)Dd);
        outs[0] = (float)(NQ * 10.0 * (double)frame_rate[0]); // log2(1024)=10
        outs[1] = (float)per_elem;
    }
}

extern "C" void kernel_launch(void* const* d_in, const int* in_sizes, int n_in,
                              void* d_out, int out_size, void* d_ws, size_t ws_size,
                              hipStream_t stream) {
    const float* x  = (const float*)d_in[0];   // (B, D, T)
    const float* cb = (const float*)d_in[1];   // (NQ, K, D)
    const int*   fr = (const int*)d_in[2];     // frame_rate

    float* outq    = (float*)d_out;                       // (B,D,T) 4194304
    float* codes_f = outq + (size_t)Bsz * Dd * Tt;        // (NQ,B,T) 262144
    float* scal    = codes_f + (size_t)NQ * BT;           // bw, penalty

    char* ws = (char*)d_ws;
    float*  resid   = (float*)ws;                              // BT*D f32
    float*  c2      = resid + (size_t)BT * Dd;                 // NQ*K f32
    double* commits = (double*)(c2 + (size_t)NQ * Kk);         // NQ f64
    char*   bswz    = (char*)(commits + NQ);                   // NQ*64*8192 B

    dim3 tb(32, 8, 1);
    k_init<<<dim3(Tt / 32, Dd / 32, Bsz), tb, 0, stream>>>(x, resid);
    k_prep<<<NQ * 256, 64, 0, stream>>>(cb, bswz);
    k_c2<<<NQ * Kk / 4, 256, 0, stream>>>(cb, c2, commits);

    k_rvq_fused<<<BT / MT, NTHR, 0, stream>>>(resid, cb, bswz, c2,
                                              codes_f, commits);

    k_final<<<dim3(Tt / 32, Dd / 32, Bsz), tb, 0, stream>>>(x, resid, outq);
    k_scalars<<<1, 64, 0, stream>>>(commits, fr, scal);
}